// Round 14
// baseline (371.811 us; speedup 1.0000x reference)
//
#include <hip/hip_runtime.h>

#define N_NODES 100000
#define N_EDGES 1600000
#define P_PARTS 8
#define S_SLICES 128
#define NP 12500     // nodes per partition
#define ES 12500     // edges per slice
#define FEAT2_OFF 12800000

typedef __attribute__((ext_vector_type(8))) short short8;
typedef __attribute__((ext_vector_type(8))) unsigned short ushort8v;
typedef __attribute__((ext_vector_type(4))) float f32x4;

__device__ inline float bf2f(unsigned short h) {
    union { unsigned int u; float f; } v; v.u = ((unsigned int)h) << 16; return v.f;
}
__device__ inline unsigned short f2bf(float f) {
    union { unsigned int u; float f; } v; v.f = f;
    unsigned int u = v.u;
    return (unsigned short)((u + 0x7fffu + ((u >> 16) & 1u)) >> 16);
}

// ---------------------------------------------------------------- partitioned LDS histograms
// packed: h[a] low16 = src count, high16 = dst count -> 50KB LDS; outputs ushort partials
__global__ __launch_bounds__(256) void hist_part_kernel(
    const int* __restrict__ src, const int* __restrict__ dst,
    unsigned short* __restrict__ part_src, unsigned short* __restrict__ part_dst) {
    __shared__ int h[NP];
    int tid = threadIdx.x;
    int p = blockIdx.x & (P_PARTS - 1), s = blockIdx.x >> 3;
    for (int j = tid; j < NP; j += 256) h[j] = 0;
    __syncthreads();
    int lo = p * NP;
    const int4* s4 = (const int4*)(src + s * ES);
    const int4* d4 = (const int4*)(dst + s * ES);
    for (int i = tid; i < ES / 4; i += 256) {
        int4 sv = s4[i];
        int4 dv = d4[i];
        int a;
        a = sv.x - lo; if ((unsigned)a < NP) atomicAdd(&h[a], 1);
        a = sv.y - lo; if ((unsigned)a < NP) atomicAdd(&h[a], 1);
        a = sv.z - lo; if ((unsigned)a < NP) atomicAdd(&h[a], 1);
        a = sv.w - lo; if ((unsigned)a < NP) atomicAdd(&h[a], 1);
        a = dv.x - lo; if ((unsigned)a < NP) atomicAdd(&h[a], 0x10000);
        a = dv.y - lo; if ((unsigned)a < NP) atomicAdd(&h[a], 0x10000);
        a = dv.z - lo; if ((unsigned)a < NP) atomicAdd(&h[a], 0x10000);
        a = dv.w - lo; if ((unsigned)a < NP) atomicAdd(&h[a], 0x10000);
    }
    __syncthreads();
    unsigned short* ps = part_src + (size_t)(p * S_SLICES + s) * NP;
    unsigned short* pd = part_dst + (size_t)(p * S_SLICES + s) * NP;
    for (int j = tid; j < NP; j += 256) {
        unsigned v = (unsigned)h[j];
        ps[j] = (unsigned short)(v & 0xFFFFu);
        pd[j] = (unsigned short)(v >> 16);
    }
}

// ---------------------------------------------------------------- reduce + prefix + norms
__global__ void reduce_prefix_norm_kernel(const unsigned short* __restrict__ part_src,
                                          unsigned short* __restrict__ part_dst,
                                          int* __restrict__ deg_in,
                                          float* __restrict__ out_norm,
                                          float* __restrict__ in_norm) {
    int n = blockIdx.x * blockDim.x + threadIdx.x;
    if (n >= N_NODES) return;
    int p = n / NP, j = n - p * NP;
    size_t base = (size_t)p * S_SLICES * NP + j;
    int so = 0;
    for (int s = 0; s < S_SLICES; s++) so += part_src[base + (size_t)s * NP];
    int run = 0;
    for (int s = 0; s < S_SLICES; s++) {
        int c = part_dst[base + (size_t)s * NP];
        part_dst[base + (size_t)s * NP] = (unsigned short)run;
        run += c;
    }
    deg_in[n] = run;
    out_norm[n] = rsqrtf((float)(so < 1 ? 1 : so));
    in_norm[n]  = rsqrtf((float)(run < 1 ? 1 : run));
}

// ---------------------------------------------------------------- 1-block scan
__global__ void scan_kernel(const int* __restrict__ deg, int* __restrict__ row_ptr) {
    __shared__ int sums[1024];
    int t = threadIdx.x;
    int s = 0;
    if (t < 1000) {
        const int4* d4 = (const int4*)(deg + t * 100);
        #pragma unroll
        for (int i = 0; i < 25; i++) { int4 v = d4[i]; s += v.x + v.y + v.z + v.w; }
    }
    sums[t] = s;
    __syncthreads();
    for (int st = 1; st < 1024; st <<= 1) {
        int v = (t >= st) ? sums[t - st] : 0;
        __syncthreads();
        sums[t] += v;
        __syncthreads();
    }
    if (t < 1000) {
        int base = (t == 0) ? 0 : sums[t - 1];
        for (int i = 0; i < 100; i++) { row_ptr[t * 100 + i] = base; base += deg[t * 100 + i]; }
    }
    if (t == 1023) row_ptr[N_NODES] = sums[1023];
}

// ---------------------------------------------------------------- atomic-free CSR fill
// packed ushort ranks: cnt[a>>1] holds two 16-bit counters -> 25KB LDS
__global__ __launch_bounds__(256) void fill_part_kernel(
    const int* __restrict__ src, const int* __restrict__ dst,
    const int* __restrict__ row_ptr, const unsigned short* __restrict__ part_dst,
    int* __restrict__ csr_src) {
    __shared__ int cnt[NP / 2];
    int tid = threadIdx.x;
    int p = blockIdx.x & (P_PARTS - 1), s = blockIdx.x >> 3;
    for (int j = tid; j < NP / 2; j += 256) cnt[j] = 0;
    __syncthreads();
    int lo = p * NP;
    const unsigned short* pd = part_dst + (size_t)(p * S_SLICES + s) * NP;
    const int4* s4 = (const int4*)(src + s * ES);
    const int4* d4 = (const int4*)(dst + s * ES);
    for (int i = tid; i < ES / 4; i += 256) {
        int4 sv = s4[i];
        int4 dv = d4[i];
        int a;
        a = dv.x - lo;
        if ((unsigned)a < NP) {
            int sh = (a & 1) << 4;
            int old = atomicAdd(&cnt[a >> 1], 1 << sh);
            int r = (old >> sh) & 0xFFFF;
            csr_src[row_ptr[lo + a] + pd[a] + r] = sv.x;
        }
        a = dv.y - lo;
        if ((unsigned)a < NP) {
            int sh = (a & 1) << 4;
            int old = atomicAdd(&cnt[a >> 1], 1 << sh);
            int r = (old >> sh) & 0xFFFF;
            csr_src[row_ptr[lo + a] + pd[a] + r] = sv.y;
        }
        a = dv.z - lo;
        if ((unsigned)a < NP) {
            int sh = (a & 1) << 4;
            int old = atomicAdd(&cnt[a >> 1], 1 << sh);
            int r = (old >> sh) & 0xFFFF;
            csr_src[row_ptr[lo + a] + pd[a] + r] = sv.z;
        }
        a = dv.w - lo;
        if ((unsigned)a < NP) {
            int sh = (a & 1) << 4;
            int old = atomicAdd(&cnt[a >> 1], 1 << sh);
            int r = (old >> sh) & 0xFFFF;
            csr_src[row_ptr[lo + a] + pd[a] + r] = sv.w;
        }
    }
}

// ---------------------------------------------------------------- merged weight prep
__global__ void prep_weights_kernel(const float* __restrict__ W1, const float* __restrict__ W2,
                                    const float* __restrict__ fc1, const float* __restrict__ fc2,
                                    unsigned short* __restrict__ Wt1, unsigned short* __restrict__ Wt2,
                                    unsigned short* __restrict__ fcb) {
    int idx = blockIdx.x * blockDim.x + threadIdx.x;
    if (idx < 32768) {
        int n = idx >> 7, k = idx & 127;
        Wt1[idx] = f2bf(W1[k * 256 + n]);
    } else if (idx < 65536) {
        int t = idx - 32768;
        int n = t >> 8, k = t & 255;
        Wt2[t] = f2bf(W2[k * 128 + n]);
    } else if (idx < 98304) {
        int t = idx - 65536;
        fcb[t] = f2bf(t < 16384 ? fc1[t] : fc2[t - 16384]);
    }
}

// ---------------------------------------------------------------- prescale x*out_norm -> bf16
// NT load of in_feat (51.2 MB, read exactly once) to avoid polluting L3 ahead of agg1
__global__ void prescale_kernel(const float* __restrict__ in, const float* __restrict__ out_norm,
                                ushort4* __restrict__ out) {
    int idx = blockIdx.x * blockDim.x + threadIdx.x;
    if (idx >= N_NODES * 32) return;
    float sc = out_norm[idx >> 5];
    f32x4 v = __builtin_nontemporal_load((const f32x4*)in + idx);
    ushort4 o;
    o.x = f2bf(v.x * sc); o.y = f2bf(v.y * sc); o.z = f2bf(v.z * sc); o.w = f2bf(v.w * sc);
    out[idx] = o;
}

// ---------------------------------------------------------------- aggregation v3b
// one wave per dst node; quarter-wave (16 lanes x ushort8 = 256B) covers one bf16 row;
// main loop 4-deep, middle loop 2-deep, single tail.
// EPI1: h_out f32 stores are non-temporal (never re-read; GEMM3 reads the bf16 copy).
template<int EPI>
__global__ __launch_bounds__(256) void aggregate_bf(
    const unsigned short* __restrict__ x, const int* __restrict__ row_ptr,
    const int* __restrict__ csr_src, const float* __restrict__ in_norm,
    const float* __restrict__ b2, float* __restrict__ outF,
    unsigned short* __restrict__ outB) {
    int wave = threadIdx.x >> 6, lane = threadIdx.x & 63;
    int n = blockIdx.x * 4 + wave;
    if (n >= N_NODES) return;
    int q = lane >> 4, ql = lane & 15;
    int s0 = row_ptr[n], s1 = row_ptr[n + 1];
    const ushort8v* xf = (const ushort8v*)x;       // 16 chunks per 128-feat row
    float a0[8], a1[8];
    #pragma unroll
    for (int j = 0; j < 8; j++) { a0[j] = 0.f; a1[j] = 0.f; }
    int i = s0 + q;
    for (; i + 12 < s1; i += 16) {
        int sA = csr_src[i],     sB = csr_src[i + 4];
        int sC = csr_src[i + 8], sD = csr_src[i + 12];
        ushort8v va = xf[(size_t)sA * 16 + ql];
        ushort8v vb = xf[(size_t)sB * 16 + ql];
        ushort8v vc = xf[(size_t)sC * 16 + ql];
        ushort8v vd = xf[(size_t)sD * 16 + ql];
        #pragma unroll
        for (int j = 0; j < 8; j++) a0[j] += bf2f(va[j]) + bf2f(vc[j]);
        #pragma unroll
        for (int j = 0; j < 8; j++) a1[j] += bf2f(vb[j]) + bf2f(vd[j]);
    }
    for (; i + 4 < s1; i += 8) {
        int sA = csr_src[i], sB = csr_src[i + 4];
        ushort8v va = xf[(size_t)sA * 16 + ql];
        ushort8v vb = xf[(size_t)sB * 16 + ql];
        #pragma unroll
        for (int j = 0; j < 8; j++) a0[j] += bf2f(va[j]);
        #pragma unroll
        for (int j = 0; j < 8; j++) a1[j] += bf2f(vb[j]);
    }
    if (i < s1) {
        ushort8v va = xf[(size_t)csr_src[i] * 16 + ql];
        #pragma unroll
        for (int j = 0; j < 8; j++) a0[j] += bf2f(va[j]);
    }
    #pragma unroll
    for (int j = 0; j < 8; j++) {
        float v = a0[j] + a1[j];
        v += __shfl_xor(v, 16);
        v += __shfl_xor(v, 32);
        a0[j] = v;
    }
    float inn = in_norm[n];
    if (EPI == 0) {
        if (q == 0) {
            ushort8v o;
            #pragma unroll
            for (int j = 0; j < 8; j++) o[j] = f2bf(a0[j] * inn);
            ((ushort8v*)outB)[(size_t)n * 16 + ql] = o;
        }
    } else {
        const float4* b4 = (const float4*)b2;
        float4 blo = b4[ql * 2], bhi = b4[ql * 2 + 1];
        float v[8];
        v[0] = fmaxf(fmaf(a0[0], inn, blo.x), 0.f);
        v[1] = fmaxf(fmaf(a0[1], inn, blo.y), 0.f);
        v[2] = fmaxf(fmaf(a0[2], inn, blo.z), 0.f);
        v[3] = fmaxf(fmaf(a0[3], inn, blo.w), 0.f);
        v[4] = fmaxf(fmaf(a0[4], inn, bhi.x), 0.f);
        v[5] = fmaxf(fmaf(a0[5], inn, bhi.y), 0.f);
        v[6] = fmaxf(fmaf(a0[6], inn, bhi.z), 0.f);
        v[7] = fmaxf(fmaf(a0[7], inn, bhi.w), 0.f);
        if (q == 0) {
            ushort8v o;
            #pragma unroll
            for (int j = 0; j < 8; j++) o[j] = f2bf(v[j]);
            ((ushort8v*)outB)[(size_t)n * 16 + ql] = o;
        } else if (q == 1) {
            f32x4 o; o.x = v[0]; o.y = v[1]; o.z = v[2]; o.w = v[3];
            __builtin_nontemporal_store(o, (f32x4*)outF + (size_t)n * 32 + ql * 2);
        } else if (q == 2) {
            f32x4 o; o.x = v[4]; o.y = v[5]; o.z = v[6]; o.w = v[7];
            __builtin_nontemporal_store(o, (f32x4*)outF + (size_t)n * 32 + ql * 2 + 1);
        }
    }
}

// ---------------------------------------------------------------- bf16 MFMA GEMM (8-wave)
// 512 threads = 8 waves, 256 rows/block; B-tile staged once in LDS (64KB -> 2 blocks/CU).
// A-operand loads are non-temporal (each row read once; keep L3 for gather sources).
// EPI: 1 = bf16(relu(v+aux[col])); 2 = bf16(v*aux[row]); 3 = f32 NT split-store feat1/feat2
template<int K, int NF, int EPI>
__global__ __launch_bounds__(512) void gemm_mfma(
    const unsigned short* __restrict__ A, const unsigned short* __restrict__ Bt,
    const float* __restrict__ aux, void* __restrict__ Cv, int ldc, int M) {
    constexpr int CH = K / 8;
    __shared__ short blds[NF * 16 * K];   // 64 KB
    int tid = threadIdx.x;
    int bn = blockIdx.x * (NF * 16);
    int bm = blockIdx.y * 256;
    {
        const short8* g = (const short8*)Bt;
        short8* l = (short8*)blds;
        for (int id = tid; id < NF * 16 * CH; id += 512) {
            int col = id / CH, kc = id % CH;
            l[col * CH + (kc ^ (col & (CH - 1)))] = g[(size_t)(bn + col) * CH + kc];
        }
    }
    __syncthreads();
    int wm = tid >> 6, lane = tid & 63;            // 8 waves x 32 rows = 256 rows
    int lr = lane & 15, kq = lane >> 4;
    int r0 = bm + wm * 32 + lr;
    int r1 = r0 + 16;
    const short8* A8 = (const short8*)A;
    size_t a0row = (size_t)(r0 < M ? r0 : 0) * CH;
    size_t a1row = (size_t)(r1 < M ? r1 : 0) * CH;
    const short8* l8 = (const short8*)blds;

    f32x4 acc[2][NF];
    #pragma unroll
    for (int m = 0; m < 2; m++)
        #pragma unroll
        for (int j = 0; j < NF; j++) acc[m][j] = (f32x4)0.f;

    short8 a0 = __builtin_nontemporal_load(&A8[a0row + kq]);
    short8 a1 = __builtin_nontemporal_load(&A8[a1row + kq]);
    for (int kc2 = 0; kc2 < K / 32; kc2++) {
        int kc = kc2 * 4 + kq;
        short8 n0, n1;
        if (kc2 + 1 < K / 32) {
            n0 = __builtin_nontemporal_load(&A8[a0row + kc + 4]);
            n1 = __builtin_nontemporal_load(&A8[a1row + kc + 4]);
        }
        #pragma unroll
        for (int nj = 0; nj < NF; nj++) {
            int col = nj * 16 + lr;
            short8 b = l8[col * CH + (kc ^ (col & (CH - 1)))];
            acc[0][nj] = __builtin_amdgcn_mfma_f32_16x16x32_bf16(a0, b, acc[0][nj], 0, 0, 0);
            acc[1][nj] = __builtin_amdgcn_mfma_f32_16x16x32_bf16(a1, b, acc[1][nj], 0, 0, 0);
        }
        a0 = n0; a1 = n1;
    }

    #pragma unroll
    for (int mi = 0; mi < 2; mi++) {
        #pragma unroll
        for (int i = 0; i < 4; i++) {
            int gr = bm + wm * 32 + mi * 16 + kq * 4 + i;
            if (gr >= M) continue;
            float sc = (EPI == 2) ? aux[gr] : 0.f;
            #pragma unroll
            for (int nj = 0; nj < NF; nj++) {
                int col = bn + nj * 16 + lr;
                float v = acc[mi][nj][i];
                if (EPI == 1)
                    ((unsigned short*)Cv)[(size_t)gr * ldc + col] = f2bf(fmaxf(v + aux[col], 0.f));
                else if (EPI == 2)
                    ((unsigned short*)Cv)[(size_t)gr * ldc + col] = f2bf(v * sc);
                else {
                    float* dstp = (float*)Cv + (size_t)(col >= 128 ? FEAT2_OFF : 0)
                                  + (size_t)gr * 128 + (col & 127);
                    __builtin_nontemporal_store(v, dstp);
                }
            }
        }
    }
}

// ================================================================ launch
extern "C" void kernel_launch(void* const* d_in, const int* in_sizes, int n_in,
                              void* d_out, int out_size, void* d_ws, size_t ws_size,
                              hipStream_t stream) {
    const float* in_feat = (const float*)d_in[0];
    const int*   src     = (const int*)d_in[1];
    const int*   dst     = (const int*)d_in[2];
    const float* W1      = (const float*)d_in[3];   // [128][256]
    const float* b1      = (const float*)d_in[4];
    const float* W2      = (const float*)d_in[5];   // [256][128]
    const float* b2      = (const float*)d_in[6];
    const float* fc1_w   = (const float*)d_in[7];
    const float* fc2_w   = (const float*)d_in[8];

    float* out = (float*)d_out;
    float* h_out = out;                              // [100000][128] f32 (final)
    float* feat1 = out + (size_t)12800000;
    // scratch aliases in d_out (lifetimes verified against writers):
    unsigned short* xs_bf   = (unsigned short*)out;              // dies before agg2 writes h
    unsigned short* agg1_bf = (unsigned short*)(out + 6400000);  // dies before agg2 writes h
    unsigned short* h1_bf   = (unsigned short*)(out + 12800000); // dies before feat1 written
    unsigned short* x2_bf   = (unsigned short*)(out + 25600000); // dies before feat2 written

    // workspace
    unsigned short* part_dst = (unsigned short*)d_ws;            // [8][128][12500] ushort
    unsigned short* part_src = part_dst + (size_t)P_PARTS * S_SLICES * NP;
    int* csr_src  = (int*)part_src;                  // alias: part_src dead after reduce
    int* deg_in   = (int*)(part_src + (size_t)P_PARTS * S_SLICES * NP);
    int* row_ptr  = deg_in + 100000;                 // 100004
    float* out_norm = (float*)(row_ptr + 100004);
    float* in_norm  = out_norm + 100000;
    unsigned short* Wt1 = (unsigned short*)(in_norm + 100000);  // [256][128]
    unsigned short* Wt2 = Wt1 + 32768;                          // [128][256]
    unsigned short* fcb = Wt2 + 32768;                          // [256][128] = [fc1b;fc2b]
    unsigned short* h_bf = fcb + 32768;                         // [100000][128]

    // CSR build — no global atomics
    hist_part_kernel<<<P_PARTS * S_SLICES, 256, 0, stream>>>(src, dst, part_src, part_dst);
    reduce_prefix_norm_kernel<<<(N_NODES + 255) / 256, 256, 0, stream>>>(
        part_src, part_dst, deg_in, out_norm, in_norm);
    scan_kernel<<<1, 1024, 0, stream>>>(deg_in, row_ptr);
    fill_part_kernel<<<P_PARTS * S_SLICES, 256, 0, stream>>>(src, dst, row_ptr, part_dst, csr_src);

    prep_weights_kernel<<<384, 256, 0, stream>>>(W1, W2, fc1_w, fc2_w, Wt1, Wt2, fcb);

    prescale_kernel<<<12500, 256, 0, stream>>>(in_feat, out_norm, (ushort4*)xs_bf);

    aggregate_bf<0><<<25000, 256, 0, stream>>>(xs_bf, row_ptr, csr_src,
                                               in_norm, nullptr, nullptr, agg1_bf);

    gemm_mfma<128, 16, 1><<<dim3(1, 391), 512, 0, stream>>>(agg1_bf, Wt1, b1, h1_bf, 256, N_NODES);
    gemm_mfma<256, 8, 2><<<dim3(1, 391), 512, 0, stream>>>(h1_bf, Wt2, out_norm, x2_bf, 128, N_NODES);

    aggregate_bf<1><<<25000, 256, 0, stream>>>(x2_bf, row_ptr, csr_src,
                                               in_norm, b2, h_out, h_bf);

    gemm_mfma<128, 16, 3><<<dim3(1, 391), 512, 0, stream>>>(h_bf, fcb, nullptr, feat1, 128, N_NODES);
}

// Round 16
// 346.168 us; speedup vs baseline: 1.0741x; 1.0741x over previous
//
#include <hip/hip_runtime.h>

#define N_NODES 100000
#define N_EDGES 1600000
#define P_PARTS 8
#define S_SLICES 128
#define NP 12500     // nodes per partition
#define ES 12500     // edges per slice
#define FEAT2_OFF 12800000

typedef __attribute__((ext_vector_type(8))) short short8;
typedef __attribute__((ext_vector_type(8))) unsigned short ushort8v;
typedef __attribute__((ext_vector_type(4))) float f32x4;

__device__ inline float bf2f(unsigned short h) {
    union { unsigned int u; float f; } v; v.u = ((unsigned int)h) << 16; return v.f;
}
__device__ inline unsigned short f2bf(float f) {
    union { unsigned int u; float f; } v; v.f = f;
    unsigned int u = v.u;
    return (unsigned short)((u + 0x7fffu + ((u >> 16) & 1u)) >> 16);
}

// ---------------------------------------------------------------- partitioned LDS histograms
// packed: h[a] low16 = src count, high16 = dst count -> 50KB LDS; outputs ushort partials
__global__ __launch_bounds__(256) void hist_part_kernel(
    const int* __restrict__ src, const int* __restrict__ dst,
    unsigned short* __restrict__ part_src, unsigned short* __restrict__ part_dst) {
    __shared__ int h[NP];
    int tid = threadIdx.x;
    int p = blockIdx.x & (P_PARTS - 1), s = blockIdx.x >> 3;
    for (int j = tid; j < NP; j += 256) h[j] = 0;
    __syncthreads();
    int lo = p * NP;
    const int4* s4 = (const int4*)(src + s * ES);
    const int4* d4 = (const int4*)(dst + s * ES);
    for (int i = tid; i < ES / 4; i += 256) {
        int4 sv = s4[i];
        int4 dv = d4[i];
        int a;
        a = sv.x - lo; if ((unsigned)a < NP) atomicAdd(&h[a], 1);
        a = sv.y - lo; if ((unsigned)a < NP) atomicAdd(&h[a], 1);
        a = sv.z - lo; if ((unsigned)a < NP) atomicAdd(&h[a], 1);
        a = sv.w - lo; if ((unsigned)a < NP) atomicAdd(&h[a], 1);
        a = dv.x - lo; if ((unsigned)a < NP) atomicAdd(&h[a], 0x10000);
        a = dv.y - lo; if ((unsigned)a < NP) atomicAdd(&h[a], 0x10000);
        a = dv.z - lo; if ((unsigned)a < NP) atomicAdd(&h[a], 0x10000);
        a = dv.w - lo; if ((unsigned)a < NP) atomicAdd(&h[a], 0x10000);
    }
    __syncthreads();
    unsigned short* ps = part_src + (size_t)(p * S_SLICES + s) * NP;
    unsigned short* pd = part_dst + (size_t)(p * S_SLICES + s) * NP;
    for (int j = tid; j < NP; j += 256) {
        unsigned v = (unsigned)h[j];
        ps[j] = (unsigned short)(v & 0xFFFFu);
        pd[j] = (unsigned short)(v >> 16);
    }
}

// ---------------------------------------------------------------- reduce + prefix + norms
__global__ void reduce_prefix_norm_kernel(const unsigned short* __restrict__ part_src,
                                          unsigned short* __restrict__ part_dst,
                                          int* __restrict__ deg_in,
                                          float* __restrict__ out_norm,
                                          float* __restrict__ in_norm) {
    int n = blockIdx.x * blockDim.x + threadIdx.x;
    if (n >= N_NODES) return;
    int p = n / NP, j = n - p * NP;
    size_t base = (size_t)p * S_SLICES * NP + j;
    int so = 0;
    for (int s = 0; s < S_SLICES; s++) so += part_src[base + (size_t)s * NP];
    int run = 0;
    for (int s = 0; s < S_SLICES; s++) {
        int c = part_dst[base + (size_t)s * NP];
        part_dst[base + (size_t)s * NP] = (unsigned short)run;
        run += c;
    }
    deg_in[n] = run;
    out_norm[n] = rsqrtf((float)(so < 1 ? 1 : so));
    in_norm[n]  = rsqrtf((float)(run < 1 ? 1 : run));
}

// ---------------------------------------------------------------- 1-block scan
__global__ void scan_kernel(const int* __restrict__ deg, int* __restrict__ row_ptr) {
    __shared__ int sums[1024];
    int t = threadIdx.x;
    int s = 0;
    if (t < 1000) {
        const int4* d4 = (const int4*)(deg + t * 100);
        #pragma unroll
        for (int i = 0; i < 25; i++) { int4 v = d4[i]; s += v.x + v.y + v.z + v.w; }
    }
    sums[t] = s;
    __syncthreads();
    for (int st = 1; st < 1024; st <<= 1) {
        int v = (t >= st) ? sums[t - st] : 0;
        __syncthreads();
        sums[t] += v;
        __syncthreads();
    }
    if (t < 1000) {
        int base = (t == 0) ? 0 : sums[t - 1];
        for (int i = 0; i < 100; i++) { row_ptr[t * 100 + i] = base; base += deg[t * 100 + i]; }
    }
    if (t == 1023) row_ptr[N_NODES] = sums[1023];
}

// ---------------------------------------------------------------- atomic-free CSR fill
// packed ushort ranks: cnt[a>>1] holds two 16-bit counters -> 25KB LDS
__global__ __launch_bounds__(256) void fill_part_kernel(
    const int* __restrict__ src, const int* __restrict__ dst,
    const int* __restrict__ row_ptr, const unsigned short* __restrict__ part_dst,
    int* __restrict__ csr_src) {
    __shared__ int cnt[NP / 2];
    int tid = threadIdx.x;
    int p = blockIdx.x & (P_PARTS - 1), s = blockIdx.x >> 3;
    for (int j = tid; j < NP / 2; j += 256) cnt[j] = 0;
    __syncthreads();
    int lo = p * NP;
    const unsigned short* pd = part_dst + (size_t)(p * S_SLICES + s) * NP;
    const int4* s4 = (const int4*)(src + s * ES);
    const int4* d4 = (const int4*)(dst + s * ES);
    for (int i = tid; i < ES / 4; i += 256) {
        int4 sv = s4[i];
        int4 dv = d4[i];
        int a;
        a = dv.x - lo;
        if ((unsigned)a < NP) {
            int sh = (a & 1) << 4;
            int old = atomicAdd(&cnt[a >> 1], 1 << sh);
            int r = (old >> sh) & 0xFFFF;
            csr_src[row_ptr[lo + a] + pd[a] + r] = sv.x;
        }
        a = dv.y - lo;
        if ((unsigned)a < NP) {
            int sh = (a & 1) << 4;
            int old = atomicAdd(&cnt[a >> 1], 1 << sh);
            int r = (old >> sh) & 0xFFFF;
            csr_src[row_ptr[lo + a] + pd[a] + r] = sv.y;
        }
        a = dv.z - lo;
        if ((unsigned)a < NP) {
            int sh = (a & 1) << 4;
            int old = atomicAdd(&cnt[a >> 1], 1 << sh);
            int r = (old >> sh) & 0xFFFF;
            csr_src[row_ptr[lo + a] + pd[a] + r] = sv.z;
        }
        a = dv.w - lo;
        if ((unsigned)a < NP) {
            int sh = (a & 1) << 4;
            int old = atomicAdd(&cnt[a >> 1], 1 << sh);
            int r = (old >> sh) & 0xFFFF;
            csr_src[row_ptr[lo + a] + pd[a] + r] = sv.w;
        }
    }
}

// ---------------------------------------------------------------- merged weight prep
__global__ void prep_weights_kernel(const float* __restrict__ W1, const float* __restrict__ W2,
                                    const float* __restrict__ fc1, const float* __restrict__ fc2,
                                    unsigned short* __restrict__ Wt1, unsigned short* __restrict__ Wt2,
                                    unsigned short* __restrict__ fcb) {
    int idx = blockIdx.x * blockDim.x + threadIdx.x;
    if (idx < 32768) {
        int n = idx >> 7, k = idx & 127;
        Wt1[idx] = f2bf(W1[k * 256 + n]);
    } else if (idx < 65536) {
        int t = idx - 32768;
        int n = t >> 8, k = t & 255;
        Wt2[t] = f2bf(W2[k * 128 + n]);
    } else if (idx < 98304) {
        int t = idx - 65536;
        fcb[t] = f2bf(t < 16384 ? fc1[t] : fc2[t - 16384]);
    }
}

// ---------------------------------------------------------------- prescale x*out_norm -> bf16
__global__ void prescale_kernel(const float4* __restrict__ in, const float* __restrict__ out_norm,
                                ushort4* __restrict__ out) {
    int idx = blockIdx.x * blockDim.x + threadIdx.x;
    if (idx >= N_NODES * 32) return;
    float sc = out_norm[idx >> 5];
    float4 v = in[idx];
    ushort4 o;
    o.x = f2bf(v.x * sc); o.y = f2bf(v.y * sc); o.z = f2bf(v.z * sc); o.w = f2bf(v.w * sc);
    out[idx] = o;
}

// ---------------------------------------------------------------- aggregation v3b
// one wave per dst node; quarter-wave (16 lanes x ushort8 = 256B) covers one bf16 row;
// main loop 4-deep, middle loop 2-deep, single tail.
template<int EPI>
__global__ __launch_bounds__(256) void aggregate_bf(
    const unsigned short* __restrict__ x, const int* __restrict__ row_ptr,
    const int* __restrict__ csr_src, const float* __restrict__ in_norm,
    const float* __restrict__ b2, float4* __restrict__ outF,
    unsigned short* __restrict__ outB) {
    int wave = threadIdx.x >> 6, lane = threadIdx.x & 63;
    int n = blockIdx.x * 4 + wave;
    if (n >= N_NODES) return;
    int q = lane >> 4, ql = lane & 15;
    int s0 = row_ptr[n], s1 = row_ptr[n + 1];
    const ushort8v* xf = (const ushort8v*)x;       // 16 chunks per 128-feat row
    float a0[8], a1[8];
    #pragma unroll
    for (int j = 0; j < 8; j++) { a0[j] = 0.f; a1[j] = 0.f; }
    int i = s0 + q;
    for (; i + 12 < s1; i += 16) {
        int sA = csr_src[i],     sB = csr_src[i + 4];
        int sC = csr_src[i + 8], sD = csr_src[i + 12];
        ushort8v va = xf[(size_t)sA * 16 + ql];
        ushort8v vb = xf[(size_t)sB * 16 + ql];
        ushort8v vc = xf[(size_t)sC * 16 + ql];
        ushort8v vd = xf[(size_t)sD * 16 + ql];
        #pragma unroll
        for (int j = 0; j < 8; j++) a0[j] += bf2f(va[j]) + bf2f(vc[j]);
        #pragma unroll
        for (int j = 0; j < 8; j++) a1[j] += bf2f(vb[j]) + bf2f(vd[j]);
    }
    for (; i + 4 < s1; i += 8) {
        int sA = csr_src[i], sB = csr_src[i + 4];
        ushort8v va = xf[(size_t)sA * 16 + ql];
        ushort8v vb = xf[(size_t)sB * 16 + ql];
        #pragma unroll
        for (int j = 0; j < 8; j++) a0[j] += bf2f(va[j]);
        #pragma unroll
        for (int j = 0; j < 8; j++) a1[j] += bf2f(vb[j]);
    }
    if (i < s1) {
        ushort8v va = xf[(size_t)csr_src[i] * 16 + ql];
        #pragma unroll
        for (int j = 0; j < 8; j++) a0[j] += bf2f(va[j]);
    }
    #pragma unroll
    for (int j = 0; j < 8; j++) {
        float v = a0[j] + a1[j];
        v += __shfl_xor(v, 16);
        v += __shfl_xor(v, 32);
        a0[j] = v;
    }
    float inn = in_norm[n];
    if (EPI == 0) {
        if (q == 0) {
            ushort8v o;
            #pragma unroll
            for (int j = 0; j < 8; j++) o[j] = f2bf(a0[j] * inn);
            ((ushort8v*)outB)[(size_t)n * 16 + ql] = o;
        }
    } else {
        const float4* b4 = (const float4*)b2;
        float4 blo = b4[ql * 2], bhi = b4[ql * 2 + 1];
        float v[8];
        v[0] = fmaxf(fmaf(a0[0], inn, blo.x), 0.f);
        v[1] = fmaxf(fmaf(a0[1], inn, blo.y), 0.f);
        v[2] = fmaxf(fmaf(a0[2], inn, blo.z), 0.f);
        v[3] = fmaxf(fmaf(a0[3], inn, blo.w), 0.f);
        v[4] = fmaxf(fmaf(a0[4], inn, bhi.x), 0.f);
        v[5] = fmaxf(fmaf(a0[5], inn, bhi.y), 0.f);
        v[6] = fmaxf(fmaf(a0[6], inn, bhi.z), 0.f);
        v[7] = fmaxf(fmaf(a0[7], inn, bhi.w), 0.f);
        if (q == 0) {
            ushort8v o;
            #pragma unroll
            for (int j = 0; j < 8; j++) o[j] = f2bf(v[j]);
            ((ushort8v*)outB)[(size_t)n * 16 + ql] = o;
        } else if (q == 1) {
            outF[(size_t)n * 32 + ql * 2] = make_float4(v[0], v[1], v[2], v[3]);
        } else if (q == 2) {
            outF[(size_t)n * 32 + ql * 2 + 1] = make_float4(v[4], v[5], v[6], v[7]);
        }
    }
}

// ---------------------------------------------------------------- bf16 MFMA GEMM (8-wave)
// 512 threads = 8 waves, 256 rows/block; B-tile staged once in LDS (64KB -> 2 blocks/CU).
// EPI: 1 = bf16(relu(v+aux[col])); 2 = bf16(v*aux[row]); 3 = f32 split-store feat1/feat2
template<int K, int NF, int EPI>
__global__ __launch_bounds__(512) void gemm_mfma(
    const unsigned short* __restrict__ A, const unsigned short* __restrict__ Bt,
    const float* __restrict__ aux, void* __restrict__ Cv, int ldc, int M) {
    constexpr int CH = K / 8;
    __shared__ short blds[NF * 16 * K];   // 64 KB
    int tid = threadIdx.x;
    int bn = blockIdx.x * (NF * 16);
    int bm = blockIdx.y * 256;
    {
        const short8* g = (const short8*)Bt;
        short8* l = (short8*)blds;
        for (int id = tid; id < NF * 16 * CH; id += 512) {
            int col = id / CH, kc = id % CH;
            l[col * CH + (kc ^ (col & (CH - 1)))] = g[(size_t)(bn + col) * CH + kc];
        }
    }
    __syncthreads();
    int wm = tid >> 6, lane = tid & 63;            // 8 waves x 32 rows = 256 rows
    int lr = lane & 15, kq = lane >> 4;
    int r0 = bm + wm * 32 + lr;
    int r1 = r0 + 16;
    const short8* A8 = (const short8*)A;
    size_t a0row = (size_t)(r0 < M ? r0 : 0) * CH;
    size_t a1row = (size_t)(r1 < M ? r1 : 0) * CH;
    const short8* l8 = (const short8*)blds;

    f32x4 acc[2][NF];
    #pragma unroll
    for (int m = 0; m < 2; m++)
        #pragma unroll
        for (int j = 0; j < NF; j++) acc[m][j] = (f32x4)0.f;

    short8 a0 = A8[a0row + kq];
    short8 a1 = A8[a1row + kq];
    for (int kc2 = 0; kc2 < K / 32; kc2++) {
        int kc = kc2 * 4 + kq;
        short8 n0, n1;
        if (kc2 + 1 < K / 32) {
            n0 = A8[a0row + kc + 4];
            n1 = A8[a1row + kc + 4];
        }
        #pragma unroll
        for (int nj = 0; nj < NF; nj++) {
            int col = nj * 16 + lr;
            short8 b = l8[col * CH + (kc ^ (col & (CH - 1)))];
            acc[0][nj] = __builtin_amdgcn_mfma_f32_16x16x32_bf16(a0, b, acc[0][nj], 0, 0, 0);
            acc[1][nj] = __builtin_amdgcn_mfma_f32_16x16x32_bf16(a1, b, acc[1][nj], 0, 0, 0);
        }
        a0 = n0; a1 = n1;
    }

    #pragma unroll
    for (int mi = 0; mi < 2; mi++) {
        #pragma unroll
        for (int i = 0; i < 4; i++) {
            int gr = bm + wm * 32 + mi * 16 + kq * 4 + i;
            if (gr >= M) continue;
            float sc = (EPI == 2) ? aux[gr] : 0.f;
            #pragma unroll
            for (int nj = 0; nj < NF; nj++) {
                int col = bn + nj * 16 + lr;
                float v = acc[mi][nj][i];
                if (EPI == 1)
                    ((unsigned short*)Cv)[(size_t)gr * ldc + col] = f2bf(fmaxf(v + aux[col], 0.f));
                else if (EPI == 2)
                    ((unsigned short*)Cv)[(size_t)gr * ldc + col] = f2bf(v * sc);
                else {
                    float* dstp = (float*)Cv + (size_t)(col >= 128 ? FEAT2_OFF : 0)
                                  + (size_t)gr * 128 + (col & 127);
                    *dstp = v;
                }
            }
        }
    }
}

// ================================================================ launch
extern "C" void kernel_launch(void* const* d_in, const int* in_sizes, int n_in,
                              void* d_out, int out_size, void* d_ws, size_t ws_size,
                              hipStream_t stream) {
    const float* in_feat = (const float*)d_in[0];
    const int*   src     = (const int*)d_in[1];
    const int*   dst     = (const int*)d_in[2];
    const float* W1      = (const float*)d_in[3];   // [128][256]
    const float* b1      = (const float*)d_in[4];
    const float* W2      = (const float*)d_in[5];   // [256][128]
    const float* b2      = (const float*)d_in[6];
    const float* fc1_w   = (const float*)d_in[7];
    const float* fc2_w   = (const float*)d_in[8];

    float* out = (float*)d_out;
    float* h_out = out;                              // [100000][128] f32 (final)
    float* feat1 = out + (size_t)12800000;
    // scratch aliases in d_out (lifetimes verified against writers):
    unsigned short* xs_bf   = (unsigned short*)out;              // dies before agg2 writes h
    unsigned short* agg1_bf = (unsigned short*)(out + 6400000);  // dies before agg2 writes h
    unsigned short* h1_bf   = (unsigned short*)(out + 12800000); // dies before feat1 written
    unsigned short* x2_bf   = (unsigned short*)(out + 25600000); // dies before feat2 written

    // workspace
    unsigned short* part_dst = (unsigned short*)d_ws;            // [8][128][12500] ushort
    unsigned short* part_src = part_dst + (size_t)P_PARTS * S_SLICES * NP;
    int* csr_src  = (int*)part_src;                  // alias: part_src dead after reduce
    int* deg_in   = (int*)(part_src + (size_t)P_PARTS * S_SLICES * NP);
    int* row_ptr  = deg_in + 100000;                 // 100004
    float* out_norm = (float*)(row_ptr + 100004);
    float* in_norm  = out_norm + 100000;
    unsigned short* Wt1 = (unsigned short*)(in_norm + 100000);  // [256][128]
    unsigned short* Wt2 = Wt1 + 32768;                          // [128][256]
    unsigned short* fcb = Wt2 + 32768;                          // [256][128] = [fc1b;fc2b]
    unsigned short* h_bf = fcb + 32768;                         // [100000][128]

    // CSR build — no global atomics
    hist_part_kernel<<<P_PARTS * S_SLICES, 256, 0, stream>>>(src, dst, part_src, part_dst);
    reduce_prefix_norm_kernel<<<(N_NODES + 255) / 256, 256, 0, stream>>>(
        part_src, part_dst, deg_in, out_norm, in_norm);
    scan_kernel<<<1, 1024, 0, stream>>>(deg_in, row_ptr);
    fill_part_kernel<<<P_PARTS * S_SLICES, 256, 0, stream>>>(src, dst, row_ptr, part_dst, csr_src);

    prep_weights_kernel<<<384, 256, 0, stream>>>(W1, W2, fc1_w, fc2_w, Wt1, Wt2, fcb);

    prescale_kernel<<<12500, 256, 0, stream>>>((const float4*)in_feat, out_norm, (ushort4*)xs_bf);

    aggregate_bf<0><<<25000, 256, 0, stream>>>(xs_bf, row_ptr, csr_src,
                                               in_norm, nullptr, nullptr, agg1_bf);

    gemm_mfma<128, 16, 1><<<dim3(1, 391), 512, 0, stream>>>(agg1_bf, Wt1, b1, h1_bf, 256, N_NODES);
    gemm_mfma<256, 8, 2><<<dim3(1, 391), 512, 0, stream>>>(h1_bf, Wt2, out_norm, x2_bf, 128, N_NODES);

    aggregate_bf<1><<<25000, 256, 0, stream>>>(x2_bf, row_ptr, csr_src,
                                               in_norm, b2, (float4*)h_out, h_bf);

    gemm_mfma<128, 16, 3><<<dim3(1, 391), 512, 0, stream>>>(h_bf, fcb, nullptr, feat1, 128, N_NODES);
}